// Round 6
// baseline (200.925 us; speedup 1.0000x reference)
//
#include <hip/hip_runtime.h>

// ALiBi bias subtraction: out[b,h,i,j] = scores[b,h,i,j] - slope(h)*(i-j)
// (offset cancels in pos_diff). B=2, H=16, S=2048 -> shift/mask index decomp.
// v6: deepen MLP 4->8 within the contiguous-chunk structure that fixed the
// channel aliasing (v5: 241->197.7us). Each block-iter: 32 KiB contiguous
// chunk, 8 independent loads in flight before any store.

typedef float f32x4 __attribute__((ext_vector_type(4)));

__device__ __forceinline__ f32x4 alibi_apply(f32x4 s, unsigned int idx4) {
    const unsigned int e = idx4 << 2;              // element index of lane's .x
    const int j = (int)(e & 2047u);                // S = 2048
    const int i = (int)((e >> 11) & 2047u);
    const int h = (int)((e >> 22) & 15u);          // H = 16
    const float slope = exp2f(-0.5f * (float)(h + 1));  // 2^(-8*(h+1)/16)
    const int d = i - j;
    f32x4 o;
    o.x = s.x - slope * (float)(d);
    o.y = s.y - slope * (float)(d - 1);
    o.z = s.z - slope * (float)(d - 2);
    o.w = s.w - slope * (float)(d - 3);
    return o;
}

__global__ __launch_bounds__(256) void alibi_kernel(const f32x4* __restrict__ in,
                                                    f32x4* __restrict__ out,
                                                    unsigned int n4) {
    // Each block-iteration: contiguous chunk of 8*256 float4s (32 KiB).
    const unsigned int chunk_elems = 8u * 256u;                 // 2048 float4s
    const unsigned int nchunks = n4 / chunk_elems;              // 16384 (exact)
    const unsigned int t = threadIdx.x;

    for (unsigned int c = blockIdx.x; c < nchunks; c += gridDim.x) {
        const unsigned int base = c * chunk_elems + t;
        f32x4 s0 = in[base];
        f32x4 s1 = in[base + 256u];
        f32x4 s2 = in[base + 512u];
        f32x4 s3 = in[base + 768u];
        f32x4 s4 = in[base + 1024u];
        f32x4 s5 = in[base + 1280u];
        f32x4 s6 = in[base + 1536u];
        f32x4 s7 = in[base + 1792u];
        out[base]          = alibi_apply(s0, base);
        out[base + 256u]   = alibi_apply(s1, base + 256u);
        out[base + 512u]   = alibi_apply(s2, base + 512u);
        out[base + 768u]   = alibi_apply(s3, base + 768u);
        out[base + 1024u]  = alibi_apply(s4, base + 1024u);
        out[base + 1280u]  = alibi_apply(s5, base + 1280u);
        out[base + 1536u]  = alibi_apply(s6, base + 1536u);
        out[base + 1792u]  = alibi_apply(s7, base + 1792u);
    }
    // Tail for non-multiple sizes (never taken for the bench shape).
    const unsigned int tail_start = nchunks * chunk_elems;
    for (unsigned int idx = tail_start + blockIdx.x * blockDim.x + t; idx < n4;
         idx += gridDim.x * blockDim.x) {
        out[idx] = alibi_apply(in[idx], idx);
    }
}

extern "C" void kernel_launch(void* const* d_in, const int* in_sizes, int n_in,
                              void* d_out, int out_size, void* d_ws, size_t ws_size,
                              hipStream_t stream) {
    const f32x4* in = (const f32x4*)d_in[0];
    f32x4* out = (f32x4*)d_out;
    const unsigned int n4 = (unsigned int)(out_size / 4);  // 33554432 float4s
    const int block = 256;
    const int grid = 2048;  // 8 blocks/CU * 256 CUs; 8 chunk-iters per block
    alibi_kernel<<<grid, block, 0, stream>>>(in, out, n4);
}

// Round 7
// 185.382 us; speedup vs baseline: 1.0838x; 1.0838x over previous
//
#include <hip/hip_runtime.h>

// ALiBi bias subtraction: out[b,h,i,j] = scores[b,h,i,j] - slope(h)*(i-j)
// (offset cancels in pos_diff). B=2, H=16, S=2048 -> shift/mask index decomp.
// v7: no-loop flat launch. v5's contiguous 4-deep MLP chunk (16 KiB) kept,
// but one chunk per BLOCK (grid=32768) instead of 16 grid-stride iterations.
// Tests whether loop control / chunk serialization was the last 14% vs the
// 6.29 TB/s copy ceiling. (v6 showed MLP depth 8 is not the lever.)

typedef float f32x4 __attribute__((ext_vector_type(4)));

__device__ __forceinline__ f32x4 alibi_apply(f32x4 s, unsigned int idx4) {
    const unsigned int e = idx4 << 2;              // element index of lane's .x
    const int j = (int)(e & 2047u);                // S = 2048
    const int i = (int)((e >> 11) & 2047u);
    const int h = (int)((e >> 22) & 15u);          // H = 16
    const float slope = exp2f(-0.5f * (float)(h + 1));  // 2^(-8*(h+1)/16)
    const int d = i - j;
    f32x4 o;
    o.x = s.x - slope * (float)(d);
    o.y = s.y - slope * (float)(d - 1);
    o.z = s.z - slope * (float)(d - 2);
    o.w = s.w - slope * (float)(d - 3);
    return o;
}

__global__ __launch_bounds__(256) void alibi_kernel(const f32x4* __restrict__ in,
                                                    f32x4* __restrict__ out,
                                                    unsigned int n4) {
    // One contiguous 16 KiB chunk (4*256 float4s) per block; no loop.
    const unsigned int base = blockIdx.x * 1024u + threadIdx.x;
    if (base + 768u >= n4) {  // guard (never taken for the bench shape)
        for (unsigned int k = 0; k < 4u; ++k) {
            unsigned int idx = base + k * 256u;
            if (idx < n4) out[idx] = alibi_apply(in[idx], idx);
        }
        return;
    }
    f32x4 s0 = in[base];
    f32x4 s1 = in[base + 256u];
    f32x4 s2 = in[base + 512u];
    f32x4 s3 = in[base + 768u];
    out[base]         = alibi_apply(s0, base);
    out[base + 256u]  = alibi_apply(s1, base + 256u);
    out[base + 512u]  = alibi_apply(s2, base + 512u);
    out[base + 768u]  = alibi_apply(s3, base + 768u);
}

extern "C" void kernel_launch(void* const* d_in, const int* in_sizes, int n_in,
                              void* d_out, int out_size, void* d_ws, size_t ws_size,
                              hipStream_t stream) {
    const f32x4* in = (const f32x4*)d_in[0];
    f32x4* out = (f32x4*)d_out;
    const unsigned int n4 = (unsigned int)(out_size / 4);  // 33554432 float4s
    const int block = 256;
    const int grid = (int)((n4 + 1023u) / 1024u);  // 32768: one 16-KiB chunk per block
    alibi_kernel<<<grid, block, 0, stream>>>(in, out, n4);
}